// Round 2
// baseline (5995.198 us; speedup 1.0000x reference)
//
#include <hip/hip_runtime.h>

// ---- static config ----
static constexpr int NN   = 128;   // dialogues
static constexpr int LL   = 64;    // utterance length
static constexpr int EE   = 300;   // embedding
static constexpr int KWIN = 40;
static constexpr int KEFF = 40;
static constexpr int NQ   = 127;   // N-1
static constexpr int NCLS = 6;

__device__ __forceinline__ float sigm(float x) { return 1.f / (1.f + __expf(-x)); }

// ---------------------------------------------------------------------------
// Gather x rows: A[r=t*128+n][0..299] = emb[ids[n*64+t]]
// ---------------------------------------------------------------------------
__global__ void k_gather_x(const float* __restrict__ emb,
                           const int* __restrict__ ids,
                           float* __restrict__ A)
{
    int r = blockIdx.x;            // t*128 + n
    int n = r & (NN - 1);
    int t = r >> 7;
    int id = ids[n * LL + t];
    const float* src = emb + (size_t)id * EE;
    float* dst = A + (size_t)r * EE;
    for (int e = threadIdx.x; e < EE; e += blockDim.x) dst[e] = src[e];
}

// ---------------------------------------------------------------------------
// f32 GEMM: C[r,c] = act( sum_k A[r,k]*B[c,k] + bias[c] )
// 128x128 tile, 8x8 micro, KT=16.
// ---------------------------------------------------------------------------
__global__ __launch_bounds__(256)
void k_gemm(const float* __restrict__ A,
            const float* __restrict__ B,
            const float* __restrict__ bias,
            float* __restrict__ C,
            int R, int Cc, int K, int actTanh)
{
    __shared__ __align__(16) float As[16][132];
    __shared__ __align__(16) float Bs[16][132];
    const int tid = threadIdx.x;
    const int r0 = blockIdx.y * 128;
    const int c0 = blockIdx.x * 128;
    const int li = tid >> 1;
    const int lk = (tid & 1) * 8;
    const int tx = tid & 15, ty = tid >> 4;
    float acc[8][8];
#pragma unroll
    for (int i = 0; i < 8; ++i)
#pragma unroll
        for (int j = 0; j < 8; ++j) acc[i][j] = 0.f;
    const int nch = (K + 15) >> 4;
    for (int ch = 0; ch < nch; ++ch) {
        const int k0 = ch * 16;
        {   // A tile
            float v[8];
            int gr = r0 + li;
            int kb = k0 + lk;
            if (gr < R && kb + 8 <= K) {
                const float* p = A + (size_t)gr * K + kb;
                *(float4*)&v[0] = *(const float4*)p;
                *(float4*)&v[4] = *(const float4*)(p + 4);
            } else {
#pragma unroll
                for (int z = 0; z < 8; ++z) {
                    int k = kb + z;
                    v[z] = (gr < R && k < K) ? A[(size_t)gr * K + k] : 0.f;
                }
            }
#pragma unroll
            for (int z = 0; z < 8; ++z) As[lk + z][li] = v[z];
        }
        {   // B tile
            float v[8];
            int gr = c0 + li;
            int kb = k0 + lk;
            if (gr < Cc && kb + 8 <= K) {
                const float* p = B + (size_t)gr * K + kb;
                *(float4*)&v[0] = *(const float4*)p;
                *(float4*)&v[4] = *(const float4*)(p + 4);
            } else {
#pragma unroll
                for (int z = 0; z < 8; ++z) {
                    int k = kb + z;
                    v[z] = (gr < Cc && k < K) ? B[(size_t)gr * K + k] : 0.f;
                }
            }
#pragma unroll
            for (int z = 0; z < 8; ++z) Bs[lk + z][li] = v[z];
        }
        __syncthreads();
#pragma unroll
        for (int kk = 0; kk < 16; ++kk) {
            float a[8], b[8];
            *(float4*)&a[0] = *(const float4*)&As[kk][ty * 8];
            *(float4*)&a[4] = *(const float4*)&As[kk][ty * 8 + 4];
            *(float4*)&b[0] = *(const float4*)&Bs[kk][tx * 8];
            *(float4*)&b[4] = *(const float4*)&Bs[kk][tx * 8 + 4];
#pragma unroll
            for (int i = 0; i < 8; ++i)
#pragma unroll
                for (int j = 0; j < 8; ++j) acc[i][j] = fmaf(a[i], b[j], acc[i][j]);
        }
        __syncthreads();
    }
#pragma unroll
    for (int i = 0; i < 8; ++i) {
        int r = r0 + ty * 8 + i;
        if (r >= R) continue;
#pragma unroll
        for (int j = 0; j < 8; ++j) {
            int c = c0 + tx * 8 + j;
            if (c >= Cc) continue;
            float v = acc[i][j];
            if (bias) v += bias[c];
            if (actTanh) v = tanhf(v);
            C[(size_t)r * Cc + c] = v;
        }
    }
}

// ---------------------------------------------------------------------------
// Utterance BiGRU scan + running max-pool. One block = 2 samples, 1 direction.
// gi: [L*128][1800] f32 (row t*128+n, col d*900+{j,j+300,j+600}), includes bih.
// maxpool: [128][600] f32 (cols: fwd 0..299, bwd 300..599)
// ---------------------------------------------------------------------------
__global__ __launch_bounds__(320)
void k_utt_scan(const float* __restrict__ Whh,
                const float* __restrict__ bhh,
                const float* __restrict__ gi,
                const int* __restrict__ lens,
                float* __restrict__ maxpool)
{
    const int d = blockIdx.y;
    const int n0 = blockIdx.x * 2;
    const int j = threadIdx.x;
    __shared__ __align__(16) float h[2][304];
    if (j < 300) { h[0][j] = 0.f; h[1][j] = 0.f; }
    __syncthreads();
    const int len0 = lens[n0], len1 = lens[n0 + 1];
    const float* W = Whh + (size_t)d * 900 * 300;
    const float* wr = W + (size_t)j * 300;
    const float* wz = W + (size_t)(j + 300) * 300;
    const float* wn = W + (size_t)(j + 600) * 300;
    float br = 0.f, bz = 0.f, bn = 0.f;
    if (j < 300) {
        br = bhh[d * 900 + j];
        bz = bhh[d * 900 + 300 + j];
        bn = bhh[d * 900 + 600 + j];
    }
    float m0 = -1e30f, m1 = -1e30f;
    for (int t = 0; t < LL; ++t) {
        float dr0 = 0, dz0 = 0, dn0 = 0, dr1 = 0, dz1 = 0, dn1 = 0;
        if (j < 300) {
            for (int k = 0; k < 300; k += 4) {
                float4 tr = *(const float4*)(wr + k);
                float4 tz = *(const float4*)(wz + k);
                float4 tn = *(const float4*)(wn + k);
                float4 h0 = *(const float4*)&h[0][k];
                float4 h1 = *(const float4*)&h[1][k];
                dr0 = fmaf(tr.x, h0.x, dr0); dr0 = fmaf(tr.y, h0.y, dr0);
                dr0 = fmaf(tr.z, h0.z, dr0); dr0 = fmaf(tr.w, h0.w, dr0);
                dr1 = fmaf(tr.x, h1.x, dr1); dr1 = fmaf(tr.y, h1.y, dr1);
                dr1 = fmaf(tr.z, h1.z, dr1); dr1 = fmaf(tr.w, h1.w, dr1);
                dz0 = fmaf(tz.x, h0.x, dz0); dz0 = fmaf(tz.y, h0.y, dz0);
                dz0 = fmaf(tz.z, h0.z, dz0); dz0 = fmaf(tz.w, h0.w, dz0);
                dz1 = fmaf(tz.x, h1.x, dz1); dz1 = fmaf(tz.y, h1.y, dz1);
                dz1 = fmaf(tz.z, h1.z, dz1); dz1 = fmaf(tz.w, h1.w, dz1);
                dn0 = fmaf(tn.x, h0.x, dn0); dn0 = fmaf(tn.y, h0.y, dn0);
                dn0 = fmaf(tn.z, h0.z, dn0); dn0 = fmaf(tn.w, h0.w, dn0);
                dn1 = fmaf(tn.x, h1.x, dn1); dn1 = fmaf(tn.y, h1.y, dn1);
                dn1 = fmaf(tn.z, h1.z, dn1); dn1 = fmaf(tn.w, h1.w, dn1);
            }
        }
        __syncthreads();
        if (j < 300) {
            if (t < len0) {
                int ts = (d == 0) ? t : (len0 - 1 - t);
                size_t row = ((size_t)(ts * NN + n0)) * 1800 + d * 900 + j;
                float r = sigm(gi[row] + dr0 + br);
                float z = sigm(gi[row + 300] + dz0 + bz);
                float nv = tanhf(gi[row + 600] + r * (dn0 + bn));
                float hv = (1.f - z) * nv + z * h[0][j];
                h[0][j] = hv;
                m0 = fmaxf(m0, hv);
            } else m0 = fmaxf(m0, 0.f);
            if (t < len1) {
                int ts = (d == 0) ? t : (len1 - 1 - t);
                size_t row = ((size_t)(ts * NN + n0 + 1)) * 1800 + d * 900 + j;
                float r = sigm(gi[row] + dr1 + br);
                float z = sigm(gi[row + 300] + dz1 + bz);
                float nv = tanhf(gi[row + 600] + r * (dn1 + bn));
                float hv = (1.f - z) * nv + z * h[1][j];
                h[1][j] = hv;
                m1 = fmaxf(m1, hv);
            } else m1 = fmaxf(m1, 0.f);
        }
        __syncthreads();
    }
    if (j < 300) {
        maxpool[(size_t)n0 * 600 + d * 300 + j] = m0;
        maxpool[(size_t)(n0 + 1) * 600 + d * 300 + j] = m1;
    }
}

// ---------------------------------------------------------------------------
// query init, ctx A build
// ---------------------------------------------------------------------------
__global__ void k_init_query(const float* __restrict__ u, float* __restrict__ query)
{
    int q = blockIdx.x;
    for (int e = threadIdx.x; e < 300; e += blockDim.x)
        query[(size_t)q * 300 + e] = u[(size_t)(q + 1) * 300 + e];
}

__global__ void k_build_ctxA(const float* __restrict__ u, float* __restrict__ Actx)
{
    int rkq = blockIdx.x;            // k*127 + q
    int k = rkq / NQ, q = rkq - k * NQ;
    int src = q + 1 - KWIN + k;
    for (int e = threadIdx.x; e < 300; e += blockDim.x)
        Actx[(size_t)rkq * 300 + e] = (src >= 0) ? u[(size_t)src * 300 + e] : 0.f;
}

// ---------------------------------------------------------------------------
// Context BiGRU scan (full length 40). Writes hout[d][q][slot][300].
// ---------------------------------------------------------------------------
__global__ __launch_bounds__(320)
void k_ctx_scan(const float* __restrict__ Whh,
                const float* __restrict__ bhh,
                const float* __restrict__ gi,   // [40*127][1800]
                float* __restrict__ hout)        // [2][127][40][300]
{
    const int d = blockIdx.y;
    const int q0 = blockIdx.x * 2;
    const int cnt = (q0 + 1 < NQ) ? 2 : 1;
    const int j = threadIdx.x;
    __shared__ __align__(16) float h[2][304];
    if (j < 300) { h[0][j] = 0.f; h[1][j] = 0.f; }
    __syncthreads();
    const float* W = Whh + (size_t)d * 900 * 300;
    const float* wr = W + (size_t)j * 300;
    const float* wz = W + (size_t)(j + 300) * 300;
    const float* wn = W + (size_t)(j + 600) * 300;
    float br = 0.f, bz = 0.f, bn = 0.f;
    if (j < 300) {
        br = bhh[d * 900 + j];
        bz = bhh[d * 900 + 300 + j];
        bn = bhh[d * 900 + 600 + j];
    }
    for (int t = 0; t < KEFF; ++t) {
        float dr0 = 0, dz0 = 0, dn0 = 0, dr1 = 0, dz1 = 0, dn1 = 0;
        if (j < 300) {
            for (int k = 0; k < 300; k += 4) {
                float4 tr = *(const float4*)(wr + k);
                float4 tz = *(const float4*)(wz + k);
                float4 tn = *(const float4*)(wn + k);
                float4 h0 = *(const float4*)&h[0][k];
                float4 h1 = *(const float4*)&h[1][k];
                dr0 = fmaf(tr.x, h0.x, dr0); dr0 = fmaf(tr.y, h0.y, dr0);
                dr0 = fmaf(tr.z, h0.z, dr0); dr0 = fmaf(tr.w, h0.w, dr0);
                dr1 = fmaf(tr.x, h1.x, dr1); dr1 = fmaf(tr.y, h1.y, dr1);
                dr1 = fmaf(tr.z, h1.z, dr1); dr1 = fmaf(tr.w, h1.w, dr1);
                dz0 = fmaf(tz.x, h0.x, dz0); dz0 = fmaf(tz.y, h0.y, dz0);
                dz0 = fmaf(tz.z, h0.z, dz0); dz0 = fmaf(tz.w, h0.w, dz0);
                dz1 = fmaf(tz.x, h1.x, dz1); dz1 = fmaf(tz.y, h1.y, dz1);
                dz1 = fmaf(tz.z, h1.z, dz1); dz1 = fmaf(tz.w, h1.w, dz1);
                dn0 = fmaf(tn.x, h0.x, dn0); dn0 = fmaf(tn.y, h0.y, dn0);
                dn0 = fmaf(tn.z, h0.z, dn0); dn0 = fmaf(tn.w, h0.w, dn0);
                dn1 = fmaf(tn.x, h1.x, dn1); dn1 = fmaf(tn.y, h1.y, dn1);
                dn1 = fmaf(tn.z, h1.z, dn1); dn1 = fmaf(tn.w, h1.w, dn1);
            }
        }
        __syncthreads();
        if (j < 300) {
            const int ts = (d == 0) ? t : (KEFF - 1 - t);
            {
                size_t row = ((size_t)(ts * NQ + q0)) * 1800 + d * 900 + j;
                float r = sigm(gi[row] + dr0 + br);
                float z = sigm(gi[row + 300] + dz0 + bz);
                float nv = tanhf(gi[row + 600] + r * (dn0 + bn));
                float hv = (1.f - z) * nv + z * h[0][j];
                h[0][j] = hv;
                hout[(((size_t)d * NQ + q0) * KEFF + ts) * 300 + j] = hv;
            }
            if (cnt == 2) {
                size_t row = ((size_t)(ts * NQ + q0 + 1)) * 1800 + d * 900 + j;
                float r = sigm(gi[row] + dr1 + br);
                float z = sigm(gi[row + 300] + dz1 + bz);
                float nv = tanhf(gi[row + 600] + r * (dn1 + bn));
                float hv = (1.f - z) * nv + z * h[1][j];
                h[1][j] = hv;
                hout[(((size_t)d * NQ + q0 + 1) * KEFF + ts) * 300 + j] = hv;
            }
        }
        __syncthreads();
    }
}

// ---------------------------------------------------------------------------
// mem_bank[q][k][j] = ctx + h_f + h_b ; also copy in (k*127+q) row order
// ---------------------------------------------------------------------------
__global__ void k_combine(const float* __restrict__ u, const float* __restrict__ hout,
                          float* __restrict__ mem_bank, float* __restrict__ mrkq)
{
    int rkq = blockIdx.x;            // k*127 + q
    int k = rkq / NQ, q = rkq - k * NQ;
    int src = q + 1 - KWIN + k;
    for (int e = threadIdx.x; e < 300; e += blockDim.x) {
        float c = (src >= 0) ? u[(size_t)src * 300 + e] : 0.f;
        float v = c + hout[((size_t)q * KEFF + k) * 300 + e]
                    + hout[(((size_t)NQ + q) * KEFF + k) * 300 + e];
        mem_bank[((size_t)q * KEFF + k) * 300 + e] = v;
        mrkq[(size_t)rkq * 300 + e] = v;
    }
}

// ---------------------------------------------------------------------------
// scores[q][k] = softmax_k( query[q]·mem_bank[q][k], masked k < 39-q )
// ---------------------------------------------------------------------------
__global__ __launch_bounds__(64)
void k_score(const float* __restrict__ query, const float* __restrict__ mem_bank,
             float* __restrict__ scores)
{
    const int q = blockIdx.x;
    __shared__ float qv[300];
    for (int e = threadIdx.x; e < 300; e += 64) qv[e] = query[(size_t)q * 300 + e];
    __syncthreads();
    int k = threadIdx.x;
    float s = -1e30f;
    if (k < KEFF) {
        const float* m = mem_bank + ((size_t)q * KEFF + k) * 300;
        float acc = 0.f;
        for (int e = 0; e < 300; ++e) acc = fmaf(qv[e], m[e], acc);
        s = (k < KWIN - 1 - q) ? -1e10f : acc;
    }
    float mx = s;
    for (int o = 32; o > 0; o >>= 1) mx = fmaxf(mx, __shfl_xor(mx, o));
    float e = (k < KEFF) ? __expf(s - mx) : 0.f;
    float sm = e;
    for (int o = 32; o > 0; o >>= 1) sm += __shfl_xor(sm, o);
    if (k < KEFF) scores[q * KEFF + k] = e / sm;
}

// ---------------------------------------------------------------------------
// AttnGRU scan (one hop, one direction per blockIdx.y, 2 samples/block)
// ---------------------------------------------------------------------------
__global__ __launch_bounds__(320)
void k_att_scan(const float* __restrict__ Urw,   // [6*300][300]
                const float* __restrict__ Uww,
                const float* __restrict__ burb,  // [6*300]
                const float* __restrict__ bub,
                const float* __restrict__ xgr,   // [5080][1800]
                const float* __restrict__ xgw,
                const float* __restrict__ scores, // [127][40]
                float* __restrict__ hbuf,         // [2][127][300]
                int hop)
{
    const int d = blockIdx.y;
    const int q0 = blockIdx.x * 2;
    const int cnt = (q0 + 1 < NQ) ? 2 : 1;
    const int j = threadIdx.x;
    const int hd = hop * 2 + d;
    __shared__ __align__(16) float h[2][304];
    if (j < 300) { h[0][j] = 0.f; h[1][j] = 0.f; }
    __syncthreads();
    const float* ur = Urw + ((size_t)hd * 300 + j) * 300;
    const float* uw = Uww + ((size_t)hd * 300 + j) * 300;
    float bur = 0.f, bu = 0.f;
    if (j < 300) { bur = burb[hd * 300 + j]; bu = bub[hd * 300 + j]; }
    for (int t = 0; t < KEFF; ++t) {
        float s0 = 0, s1 = 0, w0a = 0, w1a = 0;
        if (j < 300) {
            for (int k = 0; k < 300; k += 4) {
                float4 ta = *(const float4*)(ur + k);
                float4 tb = *(const float4*)(uw + k);
                float4 h0 = *(const float4*)&h[0][k];
                float4 h1 = *(const float4*)&h[1][k];
                s0 = fmaf(ta.x, h0.x, s0); s0 = fmaf(ta.y, h0.y, s0);
                s0 = fmaf(ta.z, h0.z, s0); s0 = fmaf(ta.w, h0.w, s0);
                s1 = fmaf(ta.x, h1.x, s1); s1 = fmaf(ta.y, h1.y, s1);
                s1 = fmaf(ta.z, h1.z, s1); s1 = fmaf(ta.w, h1.w, s1);
                w0a = fmaf(tb.x, h0.x, w0a); w0a = fmaf(tb.y, h0.y, w0a);
                w0a = fmaf(tb.z, h0.z, w0a); w0a = fmaf(tb.w, h0.w, w0a);
                w1a = fmaf(tb.x, h1.x, w1a); w1a = fmaf(tb.y, h1.y, w1a);
                w1a = fmaf(tb.z, h1.z, w1a); w1a = fmaf(tb.w, h1.w, w1a);
            }
        }
        __syncthreads();
        if (j < 300) {
            int kq = (d == 0) ? t : (KEFF - 1 - t);
            {
                int q = q0;
                float gt = scores[q * KEFF + kq];
                size_t xi = ((size_t)(kq * NQ + q)) * 1800 + (size_t)hd * 300 + j;
                float r = sigm(xgr[xi] + s0 + bur);
                float ht = tanhf(xgw[xi] + r * (w0a + bu));
                h[0][j] = gt * ht + (1.f - gt) * h[0][j];
            }
            if (cnt == 2) {
                int q = q0 + 1;
                float gt = scores[q * KEFF + kq];
                size_t xi = ((size_t)(kq * NQ + q)) * 1800 + (size_t)hd * 300 + j;
                float r = sigm(xgr[xi] + s1 + bur);
                float ht = tanhf(xgw[xi] + r * (w1a + bu));
                h[1][j] = gt * ht + (1.f - gt) * h[1][j];
            }
        }
        __syncthreads();
    }
    if (j < 300) {
        for (int g = 0; g < cnt; ++g)
            hbuf[((size_t)d * NQ + (q0 + g)) * 300 + j] = h[g][j];
    }
}

__global__ void k_qupd(float* __restrict__ query, const float* __restrict__ hbuf)
{
    int q = blockIdx.x;
    for (int e = threadIdx.x; e < 300; e += blockDim.x)
        query[(size_t)q * 300 + e] += hbuf[(size_t)q * 300 + e]
                                    + hbuf[(size_t)(NQ + q) * 300 + e];
}

// ---------------------------------------------------------------------------
// classifier: out[n][c] = s_context[n]·cls_w[c] + cls_b[c]
// ---------------------------------------------------------------------------
__global__ __launch_bounds__(64)
void k_cls(const float* __restrict__ u, const float* __restrict__ query,
           const float* __restrict__ cw, const float* __restrict__ cb,
           float* __restrict__ out)
{
    int n = blockIdx.x;
    const float* srow = (n == 0) ? u : (query + (size_t)(n - 1) * 300);
    int c = threadIdx.x & 7;
    int part = threadIdx.x >> 3;
    float p = 0.f;
    if (c < NCLS) {
        for (int e = part; e < 300; e += 8) p = fmaf(srow[e], cw[c * 300 + e], p);
    }
    p += __shfl_xor(p, 8);
    p += __shfl_xor(p, 16);
    p += __shfl_xor(p, 32);
    if (part == 0 && c < NCLS) out[n * NCLS + c] = p + cb[c];
}

// ---------------------------------------------------------------------------
extern "C" void kernel_launch(void* const* d_in, const int* in_sizes, int n_in,
                              void* d_out, int out_size, void* d_ws, size_t ws_size,
                              hipStream_t stream)
{
    const int* ids  = (const int*)d_in[0];
    const int* lens = (const int*)d_in[1];
    const float* emb   = (const float*)d_in[2];
    const float* uWih  = (const float*)d_in[3];
    const float* uWhh  = (const float*)d_in[4];
    const float* ubih  = (const float*)d_in[5];
    const float* ubhh  = (const float*)d_in[6];
    const float* linw  = (const float*)d_in[7];
    const float* linb  = (const float*)d_in[8];
    const float* cWih  = (const float*)d_in[9];
    const float* cWhh  = (const float*)d_in[10];
    const float* cbih  = (const float*)d_in[11];
    const float* cbhh  = (const float*)d_in[12];
    const float* aWr_w = (const float*)d_in[13];
    const float* aWr_b = (const float*)d_in[14];
    const float* aUr_w = (const float*)d_in[15];
    const float* aUr_b = (const float*)d_in[16];
    const float* aW_w  = (const float*)d_in[17];
    const float* aW_b  = (const float*)d_in[18];
    const float* aU_w  = (const float*)d_in[19];
    const float* aU_b  = (const float*)d_in[20];
    const float* clsw  = (const float*)d_in[21];
    const float* clsb  = (const float*)d_in[22];
    float* out = (float*)d_out;
    (void)in_sizes; (void)n_in; (void)out_size; (void)ws_size;

    // ---- workspace layout (region1 reused: {Autt,giU} then {Actx,giC,hout})
    char* base = (char*)d_ws;
    float* Autt = (float*)base;                             //  9,830,400 B
    float* giU  = (float*)(base + 9830400);                 // 58,982,400 B -> ends 68,812,800
    float* Actx = (float*)base;                             //  6,096,000 B
    float* giC  = (float*)(base + 6096128);                 // 36,576,000 B -> ends 42,672,128
    float* hout = (float*)(base + 6096128 + 36576000);      // 12,192,000 B -> ends 54,864,128
    char* p2 = base + 68812800;
    size_t off = 0;
    auto alloc = [&](size_t b) -> void* {
        void* r = (void*)(p2 + off);
        off += (b + 255) & ~(size_t)255;
        return r;
    };
    float* mpool   = (float*)alloc((size_t)NN * 600 * 4);
    float* uu      = (float*)alloc((size_t)NN * 300 * 4);
    float* membank = (float*)alloc((size_t)NQ * KEFF * 300 * 4);   // [q][k][e]
    float* mrkq    = (float*)alloc((size_t)NQ * KEFF * 300 * 4);   // [k*127+q][e]
    float* xgr     = (float*)alloc((size_t)NQ * KEFF * 1800 * 4);
    float* xgw     = (float*)alloc((size_t)NQ * KEFF * 1800 * 4);
    float* query   = (float*)alloc((size_t)NQ * 300 * 4);
    float* scores  = (float*)alloc((size_t)NQ * KEFF * 4);
    float* hbuf    = (float*)alloc((size_t)2 * NQ * 300 * 4);

    const int RKQ = NQ * KEFF;  // 5080

    // 1) gather x rows, 2) utt input-gate GEMM, 3) utt BiGRU scan + maxpool
    k_gather_x<<<dim3(LL * NN), dim3(128), 0, stream>>>(emb, ids, Autt);
    k_gemm<<<dim3(15, 64), dim3(256), 0, stream>>>(Autt, uWih, ubih, giU,
                                                   LL * NN, 1800, 300, 0);
    k_utt_scan<<<dim3(64, 2), dim3(320), 0, stream>>>(uWhh, ubhh, giU, lens, mpool);
    // 4) u = tanh(maxpool @ lin_w.T + lin_b)
    k_gemm<<<dim3(3, 1), dim3(256), 0, stream>>>(mpool, linw, linb, uu,
                                                 NN, 300, 600, 1);
    // 5) query init + ctx rows
    k_init_query<<<dim3(NQ), dim3(128), 0, stream>>>(uu, query);
    k_build_ctxA<<<dim3(RKQ), dim3(128), 0, stream>>>(uu, Actx);
    // 6) ctx input-gate GEMM + ctx BiGRU scan + combine
    k_gemm<<<dim3(15, 40), dim3(256), 0, stream>>>(Actx, cWih, cbih, giC,
                                                   RKQ, 1800, 300, 0);
    k_ctx_scan<<<dim3(64, 2), dim3(320), 0, stream>>>(cWhh, cbhh, giC, hout);
    k_combine<<<dim3(RKQ), dim3(128), 0, stream>>>(uu, hout, membank, mrkq);
    // 7) attention x-projections for all hops/dirs at once
    k_gemm<<<dim3(15, 40), dim3(256), 0, stream>>>(mrkq, aWr_w, aWr_b, xgr,
                                                   RKQ, 1800, 300, 0);
    k_gemm<<<dim3(15, 40), dim3(256), 0, stream>>>(mrkq, aW_w, aW_b, xgw,
                                                   RKQ, 1800, 300, 0);
    // 8) hops
    for (int hop = 0; hop < 3; ++hop) {
        k_score<<<dim3(NQ), dim3(64), 0, stream>>>(query, membank, scores);
        k_att_scan<<<dim3(64, 2), dim3(320), 0, stream>>>(aUr_w, aU_w, aUr_b, aU_b,
                                                          xgr, xgw, scores, hbuf, hop);
        k_qupd<<<dim3(NQ), dim3(128), 0, stream>>>(query, hbuf);
    }
    // 9) classifier
    k_cls<<<dim3(NN), dim3(64), 0, stream>>>(uu, query, clsw, clsb, out);
}